// Round 2
// baseline (851.087 us; speedup 1.0000x reference)
//
#include <hip/hip_runtime.h>

typedef __bf16 bf16_t;
typedef __bf16 bf16x8 __attribute__((ext_vector_type(8)));
typedef float f32x4 __attribute__((ext_vector_type(4)));
typedef float f32x2 __attribute__((ext_vector_type(2)));

#define N_NODES 50000
#define N_PAD   50048   // padded to multiple of 128 for 128-row GEMM tiles
#define N_EDGES 400000
#define D_IN    256
#define D_HID   512
#define D_OUT   128
#define N_LAYERS 4
#define ZROW    N_PAD                  // index of the always-zero hw row (dummy gathers)
#define CSR_CAP (N_EDGES + 3 * N_NODES + 64)  // padded-slot capacity

#define AS1 __attribute__((address_space(1)))
#define AS3 __attribute__((address_space(3)))

// ---------------- init: zero deg/cursor, dummy-fill csr, zero hw[ZROW], zero dinv pad ----

__global__ void init_misc(int* __restrict__ deg, int* __restrict__ cursor,
                          int* __restrict__ csr_src, float* __restrict__ dinv,
                          bf16_t* __restrict__ hw) {
    int idx = blockIdx.x * blockDim.x + threadIdx.x;
    if (idx < CSR_CAP) csr_src[idx] = ZROW;
    if (idx < N_NODES) { deg[idx] = 0; cursor[idx] = 0; }
    if (idx < N_PAD - N_NODES) dinv[N_NODES + idx] = 0.0f;
    if (idx < D_HID / 2) ((unsigned*)(hw + (size_t)ZROW * D_HID))[idx] = 0u;
}

// ---------------- fp32 -> bf16 conversion (flat, for x) ----------------

__global__ void f32_to_bf16(const float* __restrict__ in, bf16_t* __restrict__ out, int n) {
    int idx = (blockIdx.x * blockDim.x + threadIdx.x) * 4;
    if (idx + 3 < n) {
        float4 v = *reinterpret_cast<const float4*>(in + idx);
        bf16_t o[4] = {(bf16_t)v.x, (bf16_t)v.y, (bf16_t)v.z, (bf16_t)v.w};
        *reinterpret_cast<uint2*>(out + idx) = *reinterpret_cast<const uint2*>(o);
    } else {
        for (int j = idx; j < n; j++) out[j] = (bf16_t)in[j];
    }
}

// ---------------- batched fp32 [R][C] -> bf16 transposed [C][R] for all weights --------
// z: 0 = W1 (256x512), 1..4 = Wc layer (512x512), 5 = W2 (512x128)

__global__ void transpose_all(const float* __restrict__ W1, const float* __restrict__ Wc,
                              const float* __restrict__ W2, bf16_t* __restrict__ W1t,
                              bf16_t* __restrict__ Wct, bf16_t* __restrict__ W2t) {
    const float* in; bf16_t* out; int R, C;
    const int z = blockIdx.z;
    if (z == 0)      { in = W1; out = W1t; R = D_IN;  C = D_HID; }
    else if (z <= 4) { in = Wc + (size_t)(z - 1) * D_HID * D_HID;
                       out = Wct + (size_t)(z - 1) * D_HID * D_HID; R = D_HID; C = D_HID; }
    else             { in = W2; out = W2t; R = D_HID; C = D_OUT; }

    const int c0 = blockIdx.x * 32;
    const int r0 = blockIdx.y * 32;
    if (c0 >= C || r0 >= R) return;
    __shared__ float tile[32][33];
    for (int i = threadIdx.y; i < 32; i += 8)
        tile[i][threadIdx.x] = in[(size_t)(r0 + i) * C + c0 + threadIdx.x];
    __syncthreads();
    for (int i = threadIdx.y; i < 32; i += 8)
        out[(size_t)(c0 + i) * R + r0 + threadIdx.x] = (bf16_t)tile[threadIdx.x][i];
}

// ---------------- degree / padded CSR build ----------------

__global__ void count_deg(const int* __restrict__ dst, int* __restrict__ deg, int E) {
    int e = blockIdx.x * blockDim.x + threadIdx.x;
    if (e < E) atomicAdd(&deg[dst[e]], 1);
}

__global__ void scan_reduce(const int* __restrict__ deg, int* __restrict__ partial, int N) {
    __shared__ int red[256];
    int base = blockIdx.x * 1024;
    int s = 0;
    for (int i = threadIdx.x; i < 1024; i += 256) {
        int idx = base + i;
        s += (idx < N) ? ((deg[idx] + 3) & ~3) : 0;   // padded slots
    }
    red[threadIdx.x] = s;
    __syncthreads();
    for (int off = 128; off > 0; off >>= 1) {
        if (threadIdx.x < off) red[threadIdx.x] += red[threadIdx.x + off];
        __syncthreads();
    }
    if (threadIdx.x == 0) partial[blockIdx.x] = red[0];
}

__global__ void scan_partials(int* __restrict__ partial, int nb,
                              int* __restrict__ row_start, int N) {
    if (threadIdx.x == 0 && blockIdx.x == 0) {
        int acc = 0;
        for (int i = 0; i < nb; i++) { int v = partial[i]; partial[i] = acc; acc += v; }
        row_start[N] = acc;   // total padded slots
    }
}

__global__ void scan_chunks(const int* __restrict__ deg, const int* __restrict__ partial,
                            int* __restrict__ row_start, float* __restrict__ dinv, int N) {
    __shared__ int buf[2][1024];
    int t = threadIdx.x;
    int gid = blockIdx.x * 1024 + t;
    int d = (gid < N) ? deg[gid] : 0;
    int v = (gid < N) ? ((d + 3) & ~3) : 0;           // padded slots
    int cur = 0;
    buf[0][t] = v;
    __syncthreads();
    for (int off = 1; off < 1024; off <<= 1) {
        int nxt = cur ^ 1;
        int val = buf[cur][t];
        if (t >= off) val += buf[cur][t - off];
        buf[nxt][t] = val;
        cur = nxt;
        __syncthreads();
    }
    int incl = buf[cur][t];
    if (gid < N) {
        row_start[gid] = partial[blockIdx.x] + incl - v;  // exclusive
        dinv[gid] = rsqrtf((float)(d + 1));               // +1 self loop
    }
}

__global__ void fill_csr(const int* __restrict__ ei, int E,
                         const int* __restrict__ row_start,
                         int* __restrict__ cursor, int* __restrict__ csr_src) {
    int e = blockIdx.x * blockDim.x + threadIdx.x;
    if (e < E) {
        int s = ei[e];
        int d = ei[E + e];
        int pos = atomicAdd(&cursor[d], 1);
        csr_src[row_start[d] + pos] = s;
    }
}

// ---------------- GEMM: C = act(rowscale * (A @ BT^T) + bias) ----------------
// A: [M_pad][K] bf16. BT: [N][K] bf16 (pre-transposed). Block tile 128 x 128,
// 4 waves each 64x64 (acc 64 f32 -> AGPR), BK=64, global_load_lds width=16.
// LDS XOR-swizzled (chunk c of row r holds k-group c^(r&7)): conflict-free reads.
// XCD swizzle (gridDim.x==4): the 4 blocks sharing A-rows get ids == same (mod 8)
// so they land on the same XCD L2 -> A fetched into 1 L2 instead of 4.
// PAIR: each block processes TWO vertically-adjacent 128-row tiles (rep loop).
// Rationale: capacity is 4 blocks/CU (32KB LDS, VGPR<=128) = 1024 resident;
// a 4x391=1564 grid runs 1.53 dispatch batches (~76% util). 4x196=784 fits in
// ONE batch (~3 blocks/CU, which m114/m97 showed saturates pipeline overlap).

template <bool F32OUT, bool RELU, bool PAIR>
__global__ __launch_bounds__(256, 4) void gemm_tile(
    const bf16_t* __restrict__ A, const bf16_t* __restrict__ BT,
    const float* __restrict__ bias, const float* __restrict__ rowscale,
    void* __restrict__ Cv, int M, int N, int K)
{
    __shared__ __align__(16) char smem[32768];  // sA 16KB + sB 16KB; epilogue reuse
    bf16_t* sA = (bf16_t*)smem;
    bf16_t* sB = (bf16_t*)(smem + 128 * 128);
    bf16_t* sC = (bf16_t*)smem;                 // 64 x 136 bf16 = 17.4 KB

    int bxi, byi;
    if (gridDim.x == 4) {
        const int bid = blockIdx.y * 4 + blockIdx.x;     // dispatch-linear id
        const int T0 = (int)(gridDim.y * 4) & ~31;
        if (bid < T0) { int q = bid >> 5, r = bid & 31; byi = q * 8 + (r & 7); bxi = r >> 3; }
        else          { int t = bid - T0; byi = (T0 >> 2) + (t >> 2); bxi = t & 3; }
    } else { bxi = blockIdx.x; byi = blockIdx.y; }

    const int tid  = threadIdx.x;
    const int lane = tid & 63;
    const int wave = tid >> 6;
    const int bn = bxi * 128;
    const int wm = (wave & 1) * 64;
    const int wn = (wave >> 1) * 64;
    const int lm = lane & 15;
    const int lq = lane >> 4;

    // staging: each 1KB wave-load covers 8 rows x 8 chunks; lane (r8,c8)
    const int r8 = lane >> 3;
    const int c8 = lane & 7;
    const int ksw = (c8 ^ r8) * 8;              // swizzled k-offset (elements)

    const int bm_base = byi * (PAIR ? 256 : 128);
    const int nrep = PAIR ? 2 : 1;

    for (int rep = 0; rep < nrep; rep++) {
        const int bm = bm_base + rep * 128;
        if (PAIR && bm >= M) break;             // M multiple of 128 for bf16-out paths
        if (rep) __syncthreads();               // prior epilogue's LDS reads drained

        f32x4 acc[4][4] = {};

        const int nkb = K >> 6;
        for (int kb = 0; kb < nkb; kb++) {
            const int k0 = kb * 64;
#pragma unroll
            for (int r = 0; r < 4; r++) {               // A: 16 groups of 8 rows
                const int g = r * 4 + wave;
                __builtin_amdgcn_global_load_lds(
                    (const AS1 unsigned int*)(A + (size_t)(bm + g * 8 + r8) * K + k0 + ksw),
                    (AS3 unsigned int*)((AS3 char*)(AS3 bf16_t*)sA + g * 1024),
                    16, 0, 0);
            }
#pragma unroll
            for (int r = 0; r < 4; r++) {               // B: 16 groups of 8 rows
                const int g = r * 4 + wave;
                __builtin_amdgcn_global_load_lds(
                    (const AS1 unsigned int*)(BT + (size_t)(bn + g * 8 + r8) * K + k0 + ksw),
                    (AS3 unsigned int*)((AS3 char*)(AS3 bf16_t*)sB + g * 1024),
                    16, 0, 0);
            }
            __syncthreads();

#pragma unroll
            for (int s = 0; s < 2; s++) {               // two K=32 steps per BK=64
                bf16x8 af[4], bfr[4];
#pragma unroll
                for (int mt = 0; mt < 4; mt++) {
                    const int R = wm + mt * 16 + lm;
                    const int g = s * 4 + lq;
                    af[mt] = *reinterpret_cast<bf16x8*>(&sA[R * 64 + ((g ^ (R & 7)) * 8)]);
                }
#pragma unroll
                for (int nt = 0; nt < 4; nt++) {
                    const int R = wn + nt * 16 + lm;
                    const int g = s * 4 + lq;
                    bfr[nt] = *reinterpret_cast<bf16x8*>(&sB[R * 64 + ((g ^ (R & 7)) * 8)]);
                }
#pragma unroll
                for (int mt = 0; mt < 4; mt++)
#pragma unroll
                    for (int nt = 0; nt < 4; nt++)
                        acc[mt][nt] = __builtin_amdgcn_mfma_f32_16x16x32_bf16(af[mt], bfr[nt], acc[mt][nt], 0, 0, 0);
            }
            __syncthreads();
        }

        if (!F32OUT) {
            // coalesced epilogue: 2 passes of 64 rows through LDS; sC row stride 136 elems
            const size_t rowbytes = (size_t)N * 2;
#pragma unroll
            for (int p = 0; p < 2; p++) {
                if (p) __syncthreads();
                if ((wave & 1) == p) {
#pragma unroll
                    for (int nt = 0; nt < 4; nt++) {
                        const int col = wn + nt * 16 + lm;
                        const float bv = bias ? bias[bn + col] : 0.0f;
#pragma unroll
                        for (int mt = 0; mt < 4; mt++) {
#pragma unroll
                            for (int r = 0; r < 4; r++) {
                                const int lrow = mt * 16 + lq * 4 + r;
                                float v = acc[mt][nt][r] + bv;
                                if (rowscale) v *= rowscale[bm + p * 64 + lrow];
                                if (RELU) v = fmaxf(v, 0.0f);
                                sC[lrow * 136 + col] = (bf16_t)v;
                            }
                        }
                    }
                }
                __syncthreads();
                char* outbase = (char*)Cv + (size_t)(bm + p * 64) * rowbytes + (size_t)bn * 2;
#pragma unroll
                for (int j = 0; j < 4; j++) {
                    const int idx = j * 4096 + tid * 16;
                    const int row = idx >> 8;            // 256 data bytes per row
                    const int colb = idx & 255;
                    *reinterpret_cast<uint4*>(outbase + (size_t)row * rowbytes + colb) =
                        *reinterpret_cast<const uint4*>((char*)sC + (size_t)row * 272 + colb);
                }
            }
        } else {
            // scattered epilogue (dnn2, fp32 out): C/D layout col=lane&15, row=lq*4+reg
#pragma unroll
            for (int nt = 0; nt < 4; nt++) {
                const int col = bn + wn + nt * 16 + lm;
                const float bv = bias ? bias[col] : 0.0f;
#pragma unroll
                for (int mt = 0; mt < 4; mt++) {
#pragma unroll
                    for (int r = 0; r < 4; r++) {
                        const int row = bm + wm + mt * 16 + lq * 4 + r;
                        if (row < M) {
                            float v = acc[mt][nt][r] + bv;
                            if (rowscale) v *= rowscale[row];
                            if (RELU) v = fmaxf(v, 0.0f);
                            ((float*)Cv)[(size_t)row * N + col] = v;
                        }
                    }
                }
            }
        }
    }
}

// ---------------- aggregation ----------------
// hw is pre-scaled: hw[s] = dinv[s] * (h W)[s]. Slots padded to x4, dummies -> ZROW (zeros).
// h_out[n] = dinv[n] * ( hw[n] + sum_slots hw[s] ) + bias
// one wave per node; lane handles 8 contiguous features (512 = 64*8).
// Main loop: 8 slots/iter -> 2 int4 index loads + 8 independent 16B gathers in flight.
// Accumulate as float2 (lo = u<<16, hi = u & 0xffff0000) -> v_pk_add_f32.
// NOTE (R1 post-mortem): 2-nodes/wave variant halved wave count -> -7%; the
// gather path is saturated (~4 TB/s TCC-miss, FETCH ~= compulsory per-XCD
// floor). This 1-node/wave form is the measured best (67 us).

__global__ __launch_bounds__(256) void aggregate(
    const bf16_t* __restrict__ hw, const float* __restrict__ dinv,
    const int* __restrict__ row_start, const int* __restrict__ csr_src,
    const float* __restrict__ bias, bf16_t* __restrict__ h_out, int N)
{
    const int n = blockIdx.x * 4 + (threadIdx.x >> 6);
    const int lane = threadIdx.x & 63;
    if (n >= N) return;

    const float dn = dinv[n];
    const char* hwb = (const char*)hw + lane * 16;

    f32x2 acc[4];
    {   // self term (already scaled by dinv[n])
        uint4 u = *reinterpret_cast<const uint4*>(hwb + ((size_t)n << 10));
        const unsigned* w = reinterpret_cast<const unsigned*>(&u);
#pragma unroll
        for (int j = 0; j < 4; j++) {
            acc[j][0] = __uint_as_float(w[j] << 16);
            acc[j][1] = __uint_as_float(w[j] & 0xffff0000u);
        }
    }

    const int beg = row_start[n];
    const int cnt = row_start[n + 1] - beg;      // multiple of 4
    const int* ip = csr_src + beg;               // 16B-aligned (beg multiple of 4)

    int i = 0;
    for (; i + 8 <= cnt; i += 8) {
        const int4 a = *reinterpret_cast<const int4*>(ip + i);
        const int4 b = *reinterpret_cast<const int4*>(ip + i + 4);
        uint4 u[8];
        u[0] = *reinterpret_cast<const uint4*>(hwb + ((size_t)a.x << 10));
        u[1] = *reinterpret_cast<const uint4*>(hwb + ((size_t)a.y << 10));
        u[2] = *reinterpret_cast<const uint4*>(hwb + ((size_t)a.z << 10));
        u[3] = *reinterpret_cast<const uint4*>(hwb + ((size_t)a.w << 10));
        u[4] = *reinterpret_cast<const uint4*>(hwb + ((size_t)b.x << 10));
        u[5] = *reinterpret_cast<const uint4*>(hwb + ((size_t)b.y << 10));
        u[6] = *reinterpret_cast<const uint4*>(hwb + ((size_t)b.z << 10));
        u[7] = *reinterpret_cast<const uint4*>(hwb + ((size_t)b.w << 10));
#pragma unroll
        for (int q = 0; q < 8; q++) {
            const unsigned* w = reinterpret_cast<const unsigned*>(&u[q]);
#pragma unroll
            for (int j = 0; j < 4; j++) {
                f32x2 v;
                v[0] = __uint_as_float(w[j] << 16);
                v[1] = __uint_as_float(w[j] & 0xffff0000u);
                acc[j] += v;
            }
        }
    }
    if (i < cnt) {                               // one final 4-slot chunk
        const int4 a = *reinterpret_cast<const int4*>(ip + i);
        uint4 u[4];
        u[0] = *reinterpret_cast<const uint4*>(hwb + ((size_t)a.x << 10));
        u[1] = *reinterpret_cast<const uint4*>(hwb + ((size_t)a.y << 10));
        u[2] = *reinterpret_cast<const uint4*>(hwb + ((size_t)a.z << 10));
        u[3] = *reinterpret_cast<const uint4*>(hwb + ((size_t)a.w << 10));
#pragma unroll
        for (int q = 0; q < 4; q++) {
            const unsigned* w = reinterpret_cast<const unsigned*>(&u[q]);
#pragma unroll
            for (int j = 0; j < 4; j++) {
                f32x2 v;
                v[0] = __uint_as_float(w[j] << 16);
                v[1] = __uint_as_float(w[j] & 0xffff0000u);
                acc[j] += v;
            }
        }
    }

    const int f = lane * 8;
    bf16_t outv[8];
#pragma unroll
    for (int j = 0; j < 4; j++) {
        outv[2 * j]     = (bf16_t)(fmaf(dn, acc[j][0], bias[f + 2 * j]));
        outv[2 * j + 1] = (bf16_t)(fmaf(dn, acc[j][1], bias[f + 2 * j + 1]));
    }
    *reinterpret_cast<uint4*>(h_out + (size_t)n * D_HID + f) = *reinterpret_cast<const uint4*>(outv);
}

// ---------------- orchestration ----------------

extern "C" void kernel_launch(void* const* d_in, const int* in_sizes, int n_in,
                              void* d_out, int out_size, void* d_ws, size_t ws_size,
                              hipStream_t stream) {
    const int N = N_NODES, E = N_EDGES;

    const float* x  = (const float*)d_in[0];
    const int*   ei = (const int*)d_in[1];
    const float* W1 = (const float*)d_in[2];
    const float* b1 = (const float*)d_in[3];
    const float* Wc = (const float*)d_in[4];
    const float* bc = (const float*)d_in[5];
    const float* W2 = (const float*)d_in[6];
    const float* b2 = (const float*)d_in[7];
    float* out = (float*)d_out;

    char* ws = (char*)d_ws;
    size_t off = 0;
    auto alloc = [&](size_t bytes) -> void* {
        void* p = ws + off;
        off += (bytes + 255) & ~(size_t)255;
        return p;
    };
    int*    deg       = (int*)alloc((size_t)N * 4);
    int*    cursor    = (int*)alloc((size_t)N * 4);
    int*    row_start = (int*)alloc((size_t)(N + 1) * 4);
    int*    partial   = (int*)alloc(256 * 4);
    float*  dinv      = (float*)alloc((size_t)N_PAD * 4);
    int*    csr_src   = (int*)alloc((size_t)CSR_CAP * 4);
    bf16_t* h         = (bf16_t*)alloc((size_t)N_PAD * D_HID * 2);
    bf16_t* hw        = (bf16_t*)alloc((size_t)(N_PAD + 1) * D_HID * 2);  // +1: ZROW
    bf16_t* xb        = (bf16_t*)alloc((size_t)N_PAD * D_IN * 2);
    bf16_t* W1t       = (bf16_t*)alloc((size_t)D_HID * D_IN * 2);
    bf16_t* Wct       = (bf16_t*)alloc((size_t)N_LAYERS * D_HID * D_HID * 2);
    bf16_t* W2t       = (bf16_t*)alloc((size_t)D_OUT * D_HID * 2);

    // init (zero deg/cursor, dummy csr fill, zero hw[ZROW], zero dinv pad)
    init_misc<<<(CSR_CAP + 255) / 256, 256, 0, stream>>>(deg, cursor, csr_src, dinv, hw);

    // conversions
    {
        int n = N * D_IN;
        f32_to_bf16<<<(n / 4 + 255) / 256, 256, 0, stream>>>(x, xb, n);
        transpose_all<<<dim3(16, 16, 6), dim3(32, 8), 0, stream>>>(W1, Wc, W2, W1t, Wct, W2t);
    }

    // padded CSR build
    count_deg<<<(E + 255) / 256, 256, 0, stream>>>(ei + E, deg, E);
    const int nch = (N + 1023) / 1024;
    scan_reduce<<<nch, 256, 0, stream>>>(deg, partial, N);
    scan_partials<<<1, 64, 0, stream>>>(partial, nch, row_start, N);
    scan_chunks<<<nch, 1024, 0, stream>>>(deg, partial, row_start, dinv, N);
    fill_csr<<<(E + 255) / 256, 256, 0, stream>>>(ei, E, row_start, cursor, csr_src);

    const dim3 blk(256);
    const int mgp = (N_PAD / 128 + 1) / 2;  // 196 paired row-tiles (2x128 rows each)

    // dnn1: h = relu(x @ W1 + b1)
    gemm_tile<false, true, true><<<dim3(D_HID / 128, mgp), blk, 0, stream>>>(
        xb, W1t, b1, nullptr, h, N_PAD, D_HID, D_IN);

    // GCN layers: hw = dinv .* (h @ Wc[i]); h = dinv .* (hw[self] + gather-sum) + bc[i]
    for (int i = 0; i < N_LAYERS; i++) {
        gemm_tile<false, false, true><<<dim3(D_HID / 128, mgp), blk, 0, stream>>>(
            h, Wct + (size_t)i * D_HID * D_HID, nullptr, dinv, hw, N_PAD, D_HID, D_HID);
        aggregate<<<(N + 3) / 4, 256, 0, stream>>>(hw, dinv, row_start, csr_src,
                                                   bc + (size_t)i * D_HID, h, N);
    }

    // dnn2: out = h @ W2 + b2 (fp32 out)
    gemm_tile<true, false, false><<<dim3(D_OUT / 128, N_PAD / 128), blk, 0, stream>>>(
        h, W2t, b2, nullptr, out, N, D_OUT, D_HID);
}

// Round 3
// 798.751 us; speedup vs baseline: 1.0655x; 1.0655x over previous
//
#include <hip/hip_runtime.h>

typedef __bf16 bf16_t;
typedef __bf16 bf16x8 __attribute__((ext_vector_type(8)));
typedef float f32x4 __attribute__((ext_vector_type(4)));
typedef float f32x2 __attribute__((ext_vector_type(2)));

#define N_NODES 50000
#define N_PAD   50048   // padded to multiple of 128 for 128-row GEMM tiles
#define N_EDGES 400000
#define D_IN    256
#define D_HID   512
#define D_OUT   128
#define N_LAYERS 4
#define ZROW    N_PAD                  // index of the always-zero hw row (dummy gathers)
#define CSR_CAP (N_EDGES + 3 * N_NODES + 64)  // padded-slot capacity

#define AS1 __attribute__((address_space(1)))
#define AS3 __attribute__((address_space(3)))

// ---------------- init: zero deg/cursor, dummy-fill csr, zero hw[ZROW], zero dinv pad ----

__global__ void init_misc(int* __restrict__ deg, int* __restrict__ cursor,
                          int* __restrict__ csr_src, float* __restrict__ dinv,
                          bf16_t* __restrict__ hw) {
    int idx = blockIdx.x * blockDim.x + threadIdx.x;
    if (idx < CSR_CAP) csr_src[idx] = ZROW;
    if (idx < N_NODES) { deg[idx] = 0; cursor[idx] = 0; }
    if (idx < N_PAD - N_NODES) dinv[N_NODES + idx] = 0.0f;
    if (idx < D_HID / 2) ((unsigned*)(hw + (size_t)ZROW * D_HID))[idx] = 0u;
}

// ---------------- fp32 -> bf16 conversion (flat, for x) ----------------

__global__ void f32_to_bf16(const float* __restrict__ in, bf16_t* __restrict__ out, int n) {
    int idx = (blockIdx.x * blockDim.x + threadIdx.x) * 4;
    if (idx + 3 < n) {
        float4 v = *reinterpret_cast<const float4*>(in + idx);
        bf16_t o[4] = {(bf16_t)v.x, (bf16_t)v.y, (bf16_t)v.z, (bf16_t)v.w};
        *reinterpret_cast<uint2*>(out + idx) = *reinterpret_cast<const uint2*>(o);
    } else {
        for (int j = idx; j < n; j++) out[j] = (bf16_t)in[j];
    }
}

// ---------------- batched fp32 [R][C] -> bf16 transposed [C][R] for all weights --------
// z: 0 = W1 (256x512), 1..4 = Wc layer (512x512), 5 = W2 (512x128)

__global__ void transpose_all(const float* __restrict__ W1, const float* __restrict__ Wc,
                              const float* __restrict__ W2, bf16_t* __restrict__ W1t,
                              bf16_t* __restrict__ Wct, bf16_t* __restrict__ W2t) {
    const float* in; bf16_t* out; int R, C;
    const int z = blockIdx.z;
    if (z == 0)      { in = W1; out = W1t; R = D_IN;  C = D_HID; }
    else if (z <= 4) { in = Wc + (size_t)(z - 1) * D_HID * D_HID;
                       out = Wct + (size_t)(z - 1) * D_HID * D_HID; R = D_HID; C = D_HID; }
    else             { in = W2; out = W2t; R = D_HID; C = D_OUT; }

    const int c0 = blockIdx.x * 32;
    const int r0 = blockIdx.y * 32;
    if (c0 >= C || r0 >= R) return;
    __shared__ float tile[32][33];
    for (int i = threadIdx.y; i < 32; i += 8)
        tile[i][threadIdx.x] = in[(size_t)(r0 + i) * C + c0 + threadIdx.x];
    __syncthreads();
    for (int i = threadIdx.y; i < 32; i += 8)
        out[(size_t)(c0 + i) * R + r0 + threadIdx.x] = (bf16_t)tile[threadIdx.x][i];
}

// ---------------- degree / padded CSR build ----------------

__global__ void count_deg(const int* __restrict__ dst, int* __restrict__ deg, int E) {
    int e = blockIdx.x * blockDim.x + threadIdx.x;
    if (e < E) atomicAdd(&deg[dst[e]], 1);
}

__global__ void scan_reduce(const int* __restrict__ deg, int* __restrict__ partial, int N) {
    __shared__ int red[256];
    int base = blockIdx.x * 1024;
    int s = 0;
    for (int i = threadIdx.x; i < 1024; i += 256) {
        int idx = base + i;
        s += (idx < N) ? ((deg[idx] + 3) & ~3) : 0;   // padded slots
    }
    red[threadIdx.x] = s;
    __syncthreads();
    for (int off = 128; off > 0; off >>= 1) {
        if (threadIdx.x < off) red[threadIdx.x] += red[threadIdx.x + off];
        __syncthreads();
    }
    if (threadIdx.x == 0) partial[blockIdx.x] = red[0];
}

__global__ void scan_partials(int* __restrict__ partial, int nb,
                              int* __restrict__ row_start, int N) {
    if (threadIdx.x == 0 && blockIdx.x == 0) {
        int acc = 0;
        for (int i = 0; i < nb; i++) { int v = partial[i]; partial[i] = acc; acc += v; }
        row_start[N] = acc;   // total padded slots
    }
}

__global__ void scan_chunks(const int* __restrict__ deg, const int* __restrict__ partial,
                            int* __restrict__ row_start, float* __restrict__ dinv, int N) {
    __shared__ int buf[2][1024];
    int t = threadIdx.x;
    int gid = blockIdx.x * 1024 + t;
    int d = (gid < N) ? deg[gid] : 0;
    int v = (gid < N) ? ((d + 3) & ~3) : 0;           // padded slots
    int cur = 0;
    buf[0][t] = v;
    __syncthreads();
    for (int off = 1; off < 1024; off <<= 1) {
        int nxt = cur ^ 1;
        int val = buf[cur][t];
        if (t >= off) val += buf[cur][t - off];
        buf[nxt][t] = val;
        cur = nxt;
        __syncthreads();
    }
    int incl = buf[cur][t];
    if (gid < N) {
        row_start[gid] = partial[blockIdx.x] + incl - v;  // exclusive
        dinv[gid] = rsqrtf((float)(d + 1));               // +1 self loop
    }
}

__global__ void fill_csr(const int* __restrict__ ei, int E,
                         const int* __restrict__ row_start,
                         int* __restrict__ cursor, int* __restrict__ csr_src) {
    int e = blockIdx.x * blockDim.x + threadIdx.x;
    if (e < E) {
        int s = ei[e];
        int d = ei[E + e];
        int pos = atomicAdd(&cursor[d], 1);
        csr_src[row_start[d] + pos] = s;
    }
}

// ---------------- GEMM: C = act(rowscale * (A @ BT^T) + bias) ----------------
// A: [M_pad][K] bf16. BT: [N][K] bf16 (pre-transposed). Block tile 128 x 128,
// 4 waves each 64x64 (acc 64 f32 -> AGPR), BK=64, global_load_lds width=16.
// LDS XOR-swizzled (chunk c of row r holds k-group c^(r&7)): conflict-free reads.
// XCD swizzle (gridDim.x==4): the 4 blocks sharing A-rows get ids == same (mod 8)
// so they land on the same XCD L2 -> A fetched into 1 L2 instead of 4.
//
// R2 post-mortem: at K=512 (8 K-iters) the serial stage->drain->compute loop is
// ~80% stall (MfmaUtil 11%, VALU 11%, HBM 1.35 TB/s) and cross-block TLP does
// not hide it. R3: 2-phase double-buffered K-loop (T3-minimum): issue next
// tile's global_load_lds BEFORE computing current; barrier's implicit vmcnt(0)
// then finds loads landed. LDS 64KB (2 buffer pairs) -> 2 blocks/CU.
// Buffers statically unrolled x2 (nkb is always even: K=512->8, K=256->4).

#define STAGE(pA, pB, k0) do {                                                      \
    _Pragma("unroll")                                                               \
    for (int r = 0; r < 4; r++) {                                                   \
        const int g = r * 4 + wave;                                                 \
        __builtin_amdgcn_global_load_lds(                                           \
            (const AS1 unsigned int*)(A + (size_t)(bm + g * 8 + r8) * K + (k0) + ksw), \
            (AS3 unsigned int*)((AS3 char*)(AS3 bf16_t*)(pA) + g * 1024), 16, 0, 0);   \
    }                                                                               \
    _Pragma("unroll")                                                               \
    for (int r = 0; r < 4; r++) {                                                   \
        const int g = r * 4 + wave;                                                 \
        __builtin_amdgcn_global_load_lds(                                           \
            (const AS1 unsigned int*)(BT + (size_t)(bn + g * 8 + r8) * K + (k0) + ksw), \
            (AS3 unsigned int*)((AS3 char*)(AS3 bf16_t*)(pB) + g * 1024), 16, 0, 0);   \
    } } while (0)

#define COMPUTE(pA, pB) do {                                                        \
    _Pragma("unroll")                                                               \
    for (int s = 0; s < 2; s++) {                                                   \
        bf16x8 af[4], bfr[4];                                                       \
        _Pragma("unroll")                                                           \
        for (int mt = 0; mt < 4; mt++) {                                            \
            const int R = wm + mt * 16 + lm;                                        \
            const int g = s * 4 + lq;                                               \
            af[mt] = *reinterpret_cast<bf16x8*>(&(pA)[R * 64 + ((g ^ (R & 7)) * 8)]); \
        }                                                                           \
        _Pragma("unroll")                                                           \
        for (int nt = 0; nt < 4; nt++) {                                            \
            const int R = wn + nt * 16 + lm;                                        \
            const int g = s * 4 + lq;                                               \
            bfr[nt] = *reinterpret_cast<bf16x8*>(&(pB)[R * 64 + ((g ^ (R & 7)) * 8)]); \
        }                                                                           \
        _Pragma("unroll")                                                           \
        for (int mt = 0; mt < 4; mt++)                                              \
            _Pragma("unroll")                                                       \
            for (int nt = 0; nt < 4; nt++)                                          \
                acc[mt][nt] = __builtin_amdgcn_mfma_f32_16x16x32_bf16(af[mt], bfr[nt], acc[mt][nt], 0, 0, 0); \
    } } while (0)

template <bool F32OUT, bool RELU>
__global__ __launch_bounds__(256, 2) void gemm_tile(
    const bf16_t* __restrict__ A, const bf16_t* __restrict__ BT,
    const float* __restrict__ bias, const float* __restrict__ rowscale,
    void* __restrict__ Cv, int M, int N, int K)
{
    __shared__ __align__(16) char smem[65536];  // 2 x (sA 16KB + sB 16KB); epilogue reuse
    bf16_t* sA0 = (bf16_t*)smem;
    bf16_t* sB0 = (bf16_t*)(smem + 16384);
    bf16_t* sA1 = (bf16_t*)(smem + 32768);
    bf16_t* sB1 = (bf16_t*)(smem + 49152);
    bf16_t* sC  = (bf16_t*)smem;                // 64 x 136 bf16 = 17.4 KB

    int bxi, byi;
    if (gridDim.x == 4) {
        const int bid = blockIdx.y * 4 + blockIdx.x;     // dispatch-linear id
        const int T0 = (int)(gridDim.y * 4) & ~31;
        if (bid < T0) { int q = bid >> 5, r = bid & 31; byi = q * 8 + (r & 7); bxi = r >> 3; }
        else          { int t = bid - T0; byi = (T0 >> 2) + (t >> 2); bxi = t & 3; }
    } else { bxi = blockIdx.x; byi = blockIdx.y; }

    const int tid  = threadIdx.x;
    const int lane = tid & 63;
    const int wave = tid >> 6;
    const int bn = bxi * 128;
    const int bm = byi * 128;
    const int wm = (wave & 1) * 64;
    const int wn = (wave >> 1) * 64;
    const int lm = lane & 15;
    const int lq = lane >> 4;

    // staging: each 1KB wave-load covers 8 rows x 8 chunks; lane (r8,c8)
    const int r8 = lane >> 3;
    const int c8 = lane & 7;
    const int ksw = (c8 ^ r8) * 8;              // swizzled k-offset (elements)

    f32x4 acc[4][4] = {};

    const int nkb = K >> 6;                     // 8 (K=512) or 4 (K=256), always even
    STAGE(sA0, sB0, 0);
    __syncthreads();                            // implicit vmcnt(0): buf0 ready
    for (int kb = 0; kb < nkb; kb += 2) {
        if (kb + 1 < nkb) STAGE(sA1, sB1, (kb + 1) * 64);   // prefetch odd step
        COMPUTE(sA0, sB0);
        __syncthreads();                        // drains: buf1 staged, buf0 reads done
        if (kb + 2 < nkb) STAGE(sA0, sB0, (kb + 2) * 64);   // prefetch next even step
        COMPUTE(sA1, sB1);                      // nkb even -> kb+1 < nkb always
        __syncthreads();                        // drains: buf0 staged, buf1 reads done
    }

    if (!F32OUT) {
        // coalesced epilogue: 2 passes of 64 rows through LDS; sC row stride 136 elems
        const size_t rowbytes = (size_t)N * 2;
#pragma unroll
        for (int p = 0; p < 2; p++) {
            if (p) __syncthreads();
            if ((wave & 1) == p) {
#pragma unroll
                for (int nt = 0; nt < 4; nt++) {
                    const int col = wn + nt * 16 + lm;
                    const float bv = bias ? bias[bn + col] : 0.0f;
#pragma unroll
                    for (int mt = 0; mt < 4; mt++) {
#pragma unroll
                        for (int r = 0; r < 4; r++) {
                            const int lrow = mt * 16 + lq * 4 + r;
                            float v = acc[mt][nt][r] + bv;
                            if (rowscale) v *= rowscale[bm + p * 64 + lrow];
                            if (RELU) v = fmaxf(v, 0.0f);
                            sC[lrow * 136 + col] = (bf16_t)v;
                        }
                    }
                }
            }
            __syncthreads();
            char* outbase = (char*)Cv + (size_t)(bm + p * 64) * rowbytes + (size_t)bn * 2;
#pragma unroll
            for (int j = 0; j < 4; j++) {
                const int idx = j * 4096 + tid * 16;
                const int row = idx >> 8;            // 256 data bytes per row
                const int colb = idx & 255;
                *reinterpret_cast<uint4*>(outbase + (size_t)row * rowbytes + colb) =
                    *reinterpret_cast<const uint4*>((char*)sC + (size_t)row * 272 + colb);
            }
        }
    } else {
        // scattered epilogue (dnn2, fp32 out): C/D layout col=lane&15, row=lq*4+reg
#pragma unroll
        for (int nt = 0; nt < 4; nt++) {
            const int col = bn + wn + nt * 16 + lm;
            const float bv = bias ? bias[col] : 0.0f;
#pragma unroll
            for (int mt = 0; mt < 4; mt++) {
#pragma unroll
                for (int r = 0; r < 4; r++) {
                    const int row = bm + wm + mt * 16 + lq * 4 + r;
                    if (row < M) {
                        float v = acc[mt][nt][r] + bv;
                        if (rowscale) v *= rowscale[row];
                        if (RELU) v = fmaxf(v, 0.0f);
                        ((float*)Cv)[(size_t)row * N + col] = v;
                    }
                }
            }
        }
    }
}

// ---------------- aggregation ----------------
// hw is pre-scaled: hw[s] = dinv[s] * (h W)[s]. Slots padded to x4, dummies -> ZROW (zeros).
// h_out[n] = dinv[n] * ( hw[n] + sum_slots hw[s] ) + bias
// one wave per node; lane handles 8 contiguous features (512 = 64*8).
// Main loop: 8 slots/iter -> 2 int4 index loads + 8 independent 16B gathers in flight.
// Accumulate as float2 (lo = u<<16, hi = u & 0xffff0000) -> v_pk_add_f32.
// NOTE (R1 post-mortem): 2-nodes/wave variant halved wave count -> -7%; the
// gather path is saturated (~4 TB/s TCC-miss, FETCH ~= compulsory per-XCD
// floor). This 1-node/wave form is the measured best (67 us).

__global__ __launch_bounds__(256) void aggregate(
    const bf16_t* __restrict__ hw, const float* __restrict__ dinv,
    const int* __restrict__ row_start, const int* __restrict__ csr_src,
    const float* __restrict__ bias, bf16_t* __restrict__ h_out, int N)
{
    const int n = blockIdx.x * 4 + (threadIdx.x >> 6);
    const int lane = threadIdx.x & 63;
    if (n >= N) return;

    const float dn = dinv[n];
    const char* hwb = (const char*)hw + lane * 16;

    f32x2 acc[4];
    {   // self term (already scaled by dinv[n])
        uint4 u = *reinterpret_cast<const uint4*>(hwb + ((size_t)n << 10));
        const unsigned* w = reinterpret_cast<const unsigned*>(&u);
#pragma unroll
        for (int j = 0; j < 4; j++) {
            acc[j][0] = __uint_as_float(w[j] << 16);
            acc[j][1] = __uint_as_float(w[j] & 0xffff0000u);
        }
    }

    const int beg = row_start[n];
    const int cnt = row_start[n + 1] - beg;      // multiple of 4
    const int* ip = csr_src + beg;               // 16B-aligned (beg multiple of 4)

    int i = 0;
    for (; i + 8 <= cnt; i += 8) {
        const int4 a = *reinterpret_cast<const int4*>(ip + i);
        const int4 b = *reinterpret_cast<const int4*>(ip + i + 4);
        uint4 u[8];
        u[0] = *reinterpret_cast<const uint4*>(hwb + ((size_t)a.x << 10));
        u[1] = *reinterpret_cast<const uint4*>(hwb + ((size_t)a.y << 10));
        u[2] = *reinterpret_cast<const uint4*>(hwb + ((size_t)a.z << 10));
        u[3] = *reinterpret_cast<const uint4*>(hwb + ((size_t)a.w << 10));
        u[4] = *reinterpret_cast<const uint4*>(hwb + ((size_t)b.x << 10));
        u[5] = *reinterpret_cast<const uint4*>(hwb + ((size_t)b.y << 10));
        u[6] = *reinterpret_cast<const uint4*>(hwb + ((size_t)b.z << 10));
        u[7] = *reinterpret_cast<const uint4*>(hwb + ((size_t)b.w << 10));
#pragma unroll
        for (int q = 0; q < 8; q++) {
            const unsigned* w = reinterpret_cast<const unsigned*>(&u[q]);
#pragma unroll
            for (int j = 0; j < 4; j++) {
                f32x2 v;
                v[0] = __uint_as_float(w[j] << 16);
                v[1] = __uint_as_float(w[j] & 0xffff0000u);
                acc[j] += v;
            }
        }
    }
    if (i < cnt) {                               // one final 4-slot chunk
        const int4 a = *reinterpret_cast<const int4*>(ip + i);
        uint4 u[4];
        u[0] = *reinterpret_cast<const uint4*>(hwb + ((size_t)a.x << 10));
        u[1] = *reinterpret_cast<const uint4*>(hwb + ((size_t)a.y << 10));
        u[2] = *reinterpret_cast<const uint4*>(hwb + ((size_t)a.z << 10));
        u[3] = *reinterpret_cast<const uint4*>(hwb + ((size_t)a.w << 10));
#pragma unroll
        for (int q = 0; q < 4; q++) {
            const unsigned* w = reinterpret_cast<const unsigned*>(&u[q]);
#pragma unroll
            for (int j = 0; j < 4; j++) {
                f32x2 v;
                v[0] = __uint_as_float(w[j] << 16);
                v[1] = __uint_as_float(w[j] & 0xffff0000u);
                acc[j] += v;
            }
        }
    }

    const int f = lane * 8;
    bf16_t outv[8];
#pragma unroll
    for (int j = 0; j < 4; j++) {
        outv[2 * j]     = (bf16_t)(fmaf(dn, acc[j][0], bias[f + 2 * j]));
        outv[2 * j + 1] = (bf16_t)(fmaf(dn, acc[j][1], bias[f + 2 * j + 1]));
    }
    *reinterpret_cast<uint4*>(h_out + (size_t)n * D_HID + f) = *reinterpret_cast<const uint4*>(outv);
}

// ---------------- orchestration ----------------

extern "C" void kernel_launch(void* const* d_in, const int* in_sizes, int n_in,
                              void* d_out, int out_size, void* d_ws, size_t ws_size,
                              hipStream_t stream) {
    const int N = N_NODES, E = N_EDGES;

    const float* x  = (const float*)d_in[0];
    const int*   ei = (const int*)d_in[1];
    const float* W1 = (const float*)d_in[2];
    const float* b1 = (const float*)d_in[3];
    const float* Wc = (const float*)d_in[4];
    const float* bc = (const float*)d_in[5];
    const float* W2 = (const float*)d_in[6];
    const float* b2 = (const float*)d_in[7];
    float* out = (float*)d_out;

    char* ws = (char*)d_ws;
    size_t off = 0;
    auto alloc = [&](size_t bytes) -> void* {
        void* p = ws + off;
        off += (bytes + 255) & ~(size_t)255;
        return p;
    };
    int*    deg       = (int*)alloc((size_t)N * 4);
    int*    cursor    = (int*)alloc((size_t)N * 4);
    int*    row_start = (int*)alloc((size_t)(N + 1) * 4);
    int*    partial   = (int*)alloc(256 * 4);
    float*  dinv      = (float*)alloc((size_t)N_PAD * 4);
    int*    csr_src   = (int*)alloc((size_t)CSR_CAP * 4);
    bf16_t* h         = (bf16_t*)alloc((size_t)N_PAD * D_HID * 2);
    bf16_t* hw        = (bf16_t*)alloc((size_t)(N_PAD + 1) * D_HID * 2);  // +1: ZROW
    bf16_t* xb        = (bf16_t*)alloc((size_t)N_PAD * D_IN * 2);
    bf16_t* W1t       = (bf16_t*)alloc((size_t)D_HID * D_IN * 2);
    bf16_t* Wct       = (bf16_t*)alloc((size_t)N_LAYERS * D_HID * D_HID * 2);
    bf16_t* W2t       = (bf16_t*)alloc((size_t)D_OUT * D_HID * 2);

    // init (zero deg/cursor, dummy csr fill, zero hw[ZROW], zero dinv pad)
    init_misc<<<(CSR_CAP + 255) / 256, 256, 0, stream>>>(deg, cursor, csr_src, dinv, hw);

    // conversions
    {
        int n = N * D_IN;
        f32_to_bf16<<<(n / 4 + 255) / 256, 256, 0, stream>>>(x, xb, n);
        transpose_all<<<dim3(16, 16, 6), dim3(32, 8), 0, stream>>>(W1, Wc, W2, W1t, Wct, W2t);
    }

    // padded CSR build
    count_deg<<<(E + 255) / 256, 256, 0, stream>>>(ei + E, deg, E);
    const int nch = (N + 1023) / 1024;
    scan_reduce<<<nch, 256, 0, stream>>>(deg, partial, N);
    scan_partials<<<1, 64, 0, stream>>>(partial, nch, row_start, N);
    scan_chunks<<<nch, 1024, 0, stream>>>(deg, partial, row_start, dinv, N);
    fill_csr<<<(E + 255) / 256, 256, 0, stream>>>(ei, E, row_start, cursor, csr_src);

    const dim3 blk(256);
    const int mg = N_PAD / 128;  // 391

    // dnn1: h = relu(x @ W1 + b1)
    gemm_tile<false, true><<<dim3(D_HID / 128, mg), blk, 0, stream>>>(
        xb, W1t, b1, nullptr, h, N_PAD, D_HID, D_IN);

    // GCN layers: hw = dinv .* (h @ Wc[i]); h = dinv .* (hw[self] + gather-sum) + bc[i]
    for (int i = 0; i < N_LAYERS; i++) {
        gemm_tile<false, false><<<dim3(D_HID / 128, mg), blk, 0, stream>>>(
            h, Wct + (size_t)i * D_HID * D_HID, nullptr, dinv, hw, N_PAD, D_HID, D_HID);
        aggregate<<<(N + 3) / 4, 256, 0, stream>>>(hw, dinv, row_start, csr_src,
                                                   bc + (size_t)i * D_HID, h, N);
    }

    // dnn2: out = h @ W2 + b2 (fp32 out)
    gemm_tile<true, false><<<dim3(D_OUT / 128, mg), blk, 0, stream>>>(
        h, W2t, b2, nullptr, out, N, D_OUT, D_HID);
}

// Round 4
// 717.561 us; speedup vs baseline: 1.1861x; 1.1131x over previous
//
#include <hip/hip_runtime.h>

typedef __bf16 bf16_t;
typedef __bf16 bf16x8 __attribute__((ext_vector_type(8)));
typedef float f32x4 __attribute__((ext_vector_type(4)));
typedef float f32x2 __attribute__((ext_vector_type(2)));

#define N_NODES 50000
#define N_PAD   50048   // padded to multiple of 128 for 128-row GEMM tiles
#define N_EDGES 400000
#define D_IN    256
#define D_HID   512
#define D_OUT   128
#define N_LAYERS 4
#define ZROW    N_PAD                  // index of the always-zero hw row (dummy gathers)
#define CSR_CAP (N_EDGES + 3 * N_NODES + 64)  // padded-slot capacity

#define AS1 __attribute__((address_space(1)))
#define AS3 __attribute__((address_space(3)))

// ---------------- init: zero deg/cursor, dummy-fill csr, zero hw[ZROW], zero dinv pad ----

__global__ void init_misc(int* __restrict__ deg, int* __restrict__ cursor,
                          int* __restrict__ csr_src, float* __restrict__ dinv,
                          bf16_t* __restrict__ hw) {
    int idx = blockIdx.x * blockDim.x + threadIdx.x;
    if (idx < CSR_CAP) csr_src[idx] = ZROW;
    if (idx < N_NODES) { deg[idx] = 0; cursor[idx] = 0; }
    if (idx < N_PAD - N_NODES) dinv[N_NODES + idx] = 0.0f;
    if (idx < D_HID / 2) ((unsigned*)(hw + (size_t)ZROW * D_HID))[idx] = 0u;
}

// ---------------- fp32 -> bf16 conversion (flat, for x) ----------------

__global__ void f32_to_bf16(const float* __restrict__ in, bf16_t* __restrict__ out, int n) {
    int idx = (blockIdx.x * blockDim.x + threadIdx.x) * 4;
    if (idx + 3 < n) {
        float4 v = *reinterpret_cast<const float4*>(in + idx);
        bf16_t o[4] = {(bf16_t)v.x, (bf16_t)v.y, (bf16_t)v.z, (bf16_t)v.w};
        *reinterpret_cast<uint2*>(out + idx) = *reinterpret_cast<const uint2*>(o);
    } else {
        for (int j = idx; j < n; j++) out[j] = (bf16_t)in[j];
    }
}

// ---------------- batched fp32 [R][C] -> bf16 transposed [C][R] for all weights --------
// z: 0 = W1 (256x512), 1..4 = Wc layer (512x512), 5 = W2 (512x128)

__global__ void transpose_all(const float* __restrict__ W1, const float* __restrict__ Wc,
                              const float* __restrict__ W2, bf16_t* __restrict__ W1t,
                              bf16_t* __restrict__ Wct, bf16_t* __restrict__ W2t) {
    const float* in; bf16_t* out; int R, C;
    const int z = blockIdx.z;
    if (z == 0)      { in = W1; out = W1t; R = D_IN;  C = D_HID; }
    else if (z <= 4) { in = Wc + (size_t)(z - 1) * D_HID * D_HID;
                       out = Wct + (size_t)(z - 1) * D_HID * D_HID; R = D_HID; C = D_HID; }
    else             { in = W2; out = W2t; R = D_HID; C = D_OUT; }

    const int c0 = blockIdx.x * 32;
    const int r0 = blockIdx.y * 32;
    if (c0 >= C || r0 >= R) return;
    __shared__ float tile[32][33];
    for (int i = threadIdx.y; i < 32; i += 8)
        tile[i][threadIdx.x] = in[(size_t)(r0 + i) * C + c0 + threadIdx.x];
    __syncthreads();
    for (int i = threadIdx.y; i < 32; i += 8)
        out[(size_t)(c0 + i) * R + r0 + threadIdx.x] = (bf16_t)tile[threadIdx.x][i];
}

// ---------------- degree / padded CSR build ----------------

__global__ void count_deg(const int* __restrict__ dst, int* __restrict__ deg, int E) {
    int e = blockIdx.x * blockDim.x + threadIdx.x;
    if (e < E) atomicAdd(&deg[dst[e]], 1);
}

__global__ void scan_reduce(const int* __restrict__ deg, int* __restrict__ partial, int N) {
    __shared__ int red[256];
    int base = blockIdx.x * 1024;
    int s = 0;
    for (int i = threadIdx.x; i < 1024; i += 256) {
        int idx = base + i;
        s += (idx < N) ? ((deg[idx] + 3) & ~3) : 0;   // padded slots
    }
    red[threadIdx.x] = s;
    __syncthreads();
    for (int off = 128; off > 0; off >>= 1) {
        if (threadIdx.x < off) red[threadIdx.x] += red[threadIdx.x + off];
        __syncthreads();
    }
    if (threadIdx.x == 0) partial[blockIdx.x] = red[0];
}

__global__ void scan_partials(int* __restrict__ partial, int nb,
                              int* __restrict__ row_start, int N) {
    if (threadIdx.x == 0 && blockIdx.x == 0) {
        int acc = 0;
        for (int i = 0; i < nb; i++) { int v = partial[i]; partial[i] = acc; acc += v; }
        row_start[N] = acc;   // total padded slots
    }
}

__global__ void scan_chunks(const int* __restrict__ deg, const int* __restrict__ partial,
                            int* __restrict__ row_start, float* __restrict__ dinv, int N) {
    __shared__ int buf[2][1024];
    int t = threadIdx.x;
    int gid = blockIdx.x * 1024 + t;
    int d = (gid < N) ? deg[gid] : 0;
    int v = (gid < N) ? ((d + 3) & ~3) : 0;           // padded slots
    int cur = 0;
    buf[0][t] = v;
    __syncthreads();
    for (int off = 1; off < 1024; off <<= 1) {
        int nxt = cur ^ 1;
        int val = buf[cur][t];
        if (t >= off) val += buf[cur][t - off];
        buf[nxt][t] = val;
        cur = nxt;
        __syncthreads();
    }
    int incl = buf[cur][t];
    if (gid < N) {
        row_start[gid] = partial[blockIdx.x] + incl - v;  // exclusive
        dinv[gid] = rsqrtf((float)(d + 1));               // +1 self loop
    }
}

__global__ void fill_csr(const int* __restrict__ ei, int E,
                         const int* __restrict__ row_start,
                         int* __restrict__ cursor, int* __restrict__ csr_src) {
    int e = blockIdx.x * blockDim.x + threadIdx.x;
    if (e < E) {
        int s = ei[e];
        int d = ei[E + e];
        int pos = atomicAdd(&cursor[d], 1);
        csr_src[row_start[d] + pos] = s;
    }
}

// ---------------- GEMM: C = act(rowscale * (A @ BT^T) + bias) ----------------
// A: [M_pad][K] bf16. BT: [N][K] bf16 (pre-transposed). Block tile 128 x 128,
// 4 waves each 64x64, BK=32 counted-vmcnt ping-pong:
//   R0: single-buffer 4 blk/CU -> ~56us (best). R3: __syncthreads-dbuf 2 blk/CU
//   -> 78us (drain kills prefetch, occupancy loss). R4: double-buffer WITHIN
//   32KB (BK=32), raw s_barrier + s_waitcnt vmcnt(4): next phase's 4 loads stay
//   in flight ACROSS the barrier; occupancy stays 4 blk/CU.
// Race-freedom: per phase {STAGE(next); vmcnt(4); barrier; COMPUTE(cur); barrier}.
//   vmcnt(4) = this wave's cur-loads done (4 newest = next's); barrier certifies
//   all waves' cur-loads done before any ds_read. Trailing barrier orders
//   COMPUTE(cur) reads before cur is restaged next phase.
// LDS granule permutation: granule (row R, k-group g) stored at index
//   R*4 + ((g + ((R&15)>>1)) & 3)  -> frag reads are exactly 2-way (free).
//   Write side inverts: lane l of load-group gl sources k-group
//   ((l&3) - ((l>>3)&3)) & 3 of row gl*16 + (l>>2). LDS dest stays linear
//   (global_load_lds: uniform base + lane*16).

#define STAGE32(pA, pB, k0) do {                                                      \
    _Pragma("unroll")                                                                 \
    for (int t = 0; t < 2; t++) {                                                     \
        const int g = wave + t * 4;                                                   \
        __builtin_amdgcn_global_load_lds(                                             \
            (const AS1 unsigned int*)(A + (size_t)(bm + g * 16 + lr) * K + (k0) + gsrc8), \
            (AS3 unsigned int*)((AS3 char*)(AS3 bf16_t*)(pA) + g * 1024), 16, 0, 0);     \
    }                                                                                 \
    _Pragma("unroll")                                                                 \
    for (int t = 0; t < 2; t++) {                                                     \
        const int g = wave + t * 4;                                                   \
        __builtin_amdgcn_global_load_lds(                                             \
            (const AS1 unsigned int*)(BT + (size_t)(bn + g * 16 + lr) * K + (k0) + gsrc8), \
            (AS3 unsigned int*)((AS3 char*)(AS3 bf16_t*)(pB) + g * 1024), 16, 0, 0);     \
    } } while (0)

#define COMPUTE32(pA, pB) do {                                                        \
    bf16x8 af[4], bfr[4];                                                             \
    _Pragma("unroll")                                                                 \
    for (int mt = 0; mt < 4; mt++)                                                    \
        af[mt] = *reinterpret_cast<bf16x8*>(&(pA)[(wm + mt * 16 + lm) * 32 + cgel]);  \
    _Pragma("unroll")                                                                 \
    for (int nt = 0; nt < 4; nt++)                                                    \
        bfr[nt] = *reinterpret_cast<bf16x8*>(&(pB)[(wn + nt * 16 + lm) * 32 + cgel]); \
    _Pragma("unroll")                                                                 \
    for (int mt = 0; mt < 4; mt++)                                                    \
        _Pragma("unroll")                                                             \
        for (int nt = 0; nt < 4; nt++)                                                \
            acc[mt][nt] = __builtin_amdgcn_mfma_f32_16x16x32_bf16(af[mt], bfr[nt], acc[mt][nt], 0, 0, 0); \
    } while (0)

// wait-then-barrier: counted vmcnt keeps next phase's loads in flight
#define WB4() do { asm volatile("s_waitcnt vmcnt(4)" ::: "memory");       \
    __builtin_amdgcn_s_barrier(); __builtin_amdgcn_sched_barrier(0); } while (0)
#define WB0() do { asm volatile("s_waitcnt vmcnt(0)" ::: "memory");       \
    __builtin_amdgcn_s_barrier(); __builtin_amdgcn_sched_barrier(0); } while (0)
#define EB()  do { __builtin_amdgcn_sched_barrier(0);                     \
    __builtin_amdgcn_s_barrier(); __builtin_amdgcn_sched_barrier(0); } while (0)

template <bool F32OUT, bool RELU>
__global__ __launch_bounds__(256, 4) void gemm_tile(
    const bf16_t* __restrict__ A, const bf16_t* __restrict__ BT,
    const float* __restrict__ bias, const float* __restrict__ rowscale,
    void* __restrict__ Cv, int M, int N, int K)
{
    __shared__ __align__(16) char smem[32768];  // 2 x (sA 8KB + sB 8KB); epilogue reuse
    bf16_t* sA0 = (bf16_t*)smem;
    bf16_t* sB0 = (bf16_t*)(smem + 8192);
    bf16_t* sA1 = (bf16_t*)(smem + 16384);
    bf16_t* sB1 = (bf16_t*)(smem + 24576);
    bf16_t* sC  = (bf16_t*)smem;                // 64 x 136 bf16 = 17.4 KB

    int bxi, byi;
    if (gridDim.x == 4) {
        const int bid = blockIdx.y * 4 + blockIdx.x;     // dispatch-linear id
        const int T0 = (int)(gridDim.y * 4) & ~31;
        if (bid < T0) { int q = bid >> 5, r = bid & 31; byi = q * 8 + (r & 7); bxi = r >> 3; }
        else          { int t = bid - T0; byi = (T0 >> 2) + (t >> 2); bxi = t & 3; }
    } else { bxi = blockIdx.x; byi = blockIdx.y; }

    const int tid  = threadIdx.x;
    const int lane = tid & 63;
    const int wave = tid >> 6;
    const int bn = bxi * 128;
    const int bm = byi * 128;
    const int wm = (wave & 1) * 64;
    const int wn = (wave >> 1) * 64;
    const int lm = lane & 15;
    const int lq = lane >> 4;

    // staging lane map: load-group gl covers rows gl*16+(l>>2), lane sources
    // k-granule ((l&3)-((l>>3)&3))&3 (inverse of the store permutation)
    const int lr    = lane >> 2;
    const int gsrc8 = ((((lane & 3) + 4) - ((lane >> 3) & 3)) & 3) * 8;
    // fragment read: granule of (row, g=lq) lives at ((lq + (lm>>1)) & 3)
    const int cgel  = ((lq + (lm >> 1)) & 3) * 8;

    f32x4 acc[4][4] = {};

    const int nkb = K >> 5;                     // 16 (K=512) or 8 (K=256), even
    STAGE32(sA0, sB0, 0);
    int kb = 0;
    for (; kb + 2 < nkb; kb += 2) {
        STAGE32(sA1, sB1, (kb + 1) * 32);
        WB4(); COMPUTE32(sA0, sB0); EB();
        STAGE32(sA0, sB0, (kb + 2) * 32);
        WB4(); COMPUTE32(sA1, sB1); EB();
    }
    STAGE32(sA1, sB1, (nkb - 1) * 32);          // kb == nkb-2 here
    WB4(); COMPUTE32(sA0, sB0); EB();
    WB0(); COMPUTE32(sA1, sB1);
    __syncthreads();                            // before epilogue smem reuse

    if (!F32OUT) {
        // coalesced epilogue: 2 passes of 64 rows through LDS; sC row stride 136 elems
        const size_t rowbytes = (size_t)N * 2;
#pragma unroll
        for (int p = 0; p < 2; p++) {
            if (p) __syncthreads();
            if ((wave & 1) == p) {
#pragma unroll
                for (int nt = 0; nt < 4; nt++) {
                    const int col = wn + nt * 16 + lm;
                    const float bv = bias ? bias[bn + col] : 0.0f;
#pragma unroll
                    for (int mt = 0; mt < 4; mt++) {
#pragma unroll
                        for (int r = 0; r < 4; r++) {
                            const int lrow = mt * 16 + lq * 4 + r;
                            float v = acc[mt][nt][r] + bv;
                            if (rowscale) v *= rowscale[bm + p * 64 + lrow];
                            if (RELU) v = fmaxf(v, 0.0f);
                            sC[lrow * 136 + col] = (bf16_t)v;
                        }
                    }
                }
            }
            __syncthreads();
            char* outbase = (char*)Cv + (size_t)(bm + p * 64) * rowbytes + (size_t)bn * 2;
#pragma unroll
            for (int j = 0; j < 4; j++) {
                const int idx = j * 4096 + tid * 16;
                const int row = idx >> 8;            // 256 data bytes per row
                const int colb = idx & 255;
                *reinterpret_cast<uint4*>(outbase + (size_t)row * rowbytes + colb) =
                    *reinterpret_cast<const uint4*>((char*)sC + (size_t)row * 272 + colb);
            }
        }
    } else {
        // scattered epilogue (dnn2, fp32 out): C/D layout col=lane&15, row=lq*4+reg
#pragma unroll
        for (int nt = 0; nt < 4; nt++) {
            const int col = bn + wn + nt * 16 + lm;
            const float bv = bias ? bias[col] : 0.0f;
#pragma unroll
            for (int mt = 0; mt < 4; mt++) {
#pragma unroll
                for (int r = 0; r < 4; r++) {
                    const int row = bm + wm + mt * 16 + lq * 4 + r;
                    if (row < M) {
                        float v = acc[mt][nt][r] + bv;
                        if (rowscale) v *= rowscale[row];
                        if (RELU) v = fmaxf(v, 0.0f);
                        ((float*)Cv)[(size_t)row * N + col] = v;
                    }
                }
            }
        }
    }
}

// ---------------- aggregation ----------------
// hw is pre-scaled: hw[s] = dinv[s] * (h W)[s]. Slots padded to x4, dummies -> ZROW (zeros).
// h_out[n] = dinv[n] * ( hw[n] + sum_slots hw[s] ) + bias
// one wave per node; lane handles 8 contiguous features (512 = 64*8).
// Main loop: 8 slots/iter -> 2 int4 index loads + 8 independent 16B gathers in flight.
// NOTE (R1 post-mortem): 2-nodes/wave variant halved wave count -> -7%; the
// gather path is saturated (~4 TB/s TCC-miss, FETCH ~= compulsory per-XCD
// floor). This 1-node/wave form is the measured best (67 us).

__global__ __launch_bounds__(256) void aggregate(
    const bf16_t* __restrict__ hw, const float* __restrict__ dinv,
    const int* __restrict__ row_start, const int* __restrict__ csr_src,
    const float* __restrict__ bias, bf16_t* __restrict__ h_out, int N)
{
    const int n = blockIdx.x * 4 + (threadIdx.x >> 6);
    const int lane = threadIdx.x & 63;
    if (n >= N) return;

    const float dn = dinv[n];
    const char* hwb = (const char*)hw + lane * 16;

    f32x2 acc[4];
    {   // self term (already scaled by dinv[n])
        uint4 u = *reinterpret_cast<const uint4*>(hwb + ((size_t)n << 10));
        const unsigned* w = reinterpret_cast<const unsigned*>(&u);
#pragma unroll
        for (int j = 0; j < 4; j++) {
            acc[j][0] = __uint_as_float(w[j] << 16);
            acc[j][1] = __uint_as_float(w[j] & 0xffff0000u);
        }
    }

    const int beg = row_start[n];
    const int cnt = row_start[n + 1] - beg;      // multiple of 4
    const int* ip = csr_src + beg;               // 16B-aligned (beg multiple of 4)

    int i = 0;
    for (; i + 8 <= cnt; i += 8) {
        const int4 a = *reinterpret_cast<const int4*>(ip + i);
        const int4 b = *reinterpret_cast<const int4*>(ip + i + 4);
        uint4 u[8];
        u[0] = *reinterpret_cast<const uint4*>(hwb + ((size_t)a.x << 10));
        u[1] = *reinterpret_cast<const uint4*>(hwb + ((size_t)a.y << 10));
        u[2] = *reinterpret_cast<const uint4*>(hwb + ((size_t)a.z << 10));
        u[3] = *reinterpret_cast<const uint4*>(hwb + ((size_t)a.w << 10));
        u[4] = *reinterpret_cast<const uint4*>(hwb + ((size_t)b.x << 10));
        u[5] = *reinterpret_cast<const uint4*>(hwb + ((size_t)b.y << 10));
        u[6] = *reinterpret_cast<const uint4*>(hwb + ((size_t)b.z << 10));
        u[7] = *reinterpret_cast<const uint4*>(hwb + ((size_t)b.w << 10));
#pragma unroll
        for (int q = 0; q < 8; q++) {
            const unsigned* w = reinterpret_cast<const unsigned*>(&u[q]);
#pragma unroll
            for (int j = 0; j < 4; j++) {
                f32x2 v;
                v[0] = __uint_as_float(w[j] << 16);
                v[1] = __uint_as_float(w[j] & 0xffff0000u);
                acc[j] += v;
            }
        }
    }
    if (i < cnt) {                               // one final 4-slot chunk
        const int4 a = *reinterpret_cast<const int4*>(ip + i);
        uint4 u[4];
        u[0] = *reinterpret_cast<const uint4*>(hwb + ((size_t)a.x << 10));
        u[1] = *reinterpret_cast<const uint4*>(hwb + ((size_t)a.y << 10));
        u[2] = *reinterpret_cast<const uint4*>(hwb + ((size_t)a.z << 10));
        u[3] = *reinterpret_cast<const uint4*>(hwb + ((size_t)a.w << 10));
#pragma unroll
        for (int q = 0; q < 4; q++) {
            const unsigned* w = reinterpret_cast<const unsigned*>(&u[q]);
#pragma unroll
            for (int j = 0; j < 4; j++) {
                f32x2 v;
                v[0] = __uint_as_float(w[j] << 16);
                v[1] = __uint_as_float(w[j] & 0xffff0000u);
                acc[j] += v;
            }
        }
    }

    const int f = lane * 8;
    bf16_t outv[8];
#pragma unroll
    for (int j = 0; j < 4; j++) {
        outv[2 * j]     = (bf16_t)(fmaf(dn, acc[j][0], bias[f + 2 * j]));
        outv[2 * j + 1] = (bf16_t)(fmaf(dn, acc[j][1], bias[f + 2 * j + 1]));
    }
    *reinterpret_cast<uint4*>(h_out + (size_t)n * D_HID + f) = *reinterpret_cast<const uint4*>(outv);
}

// ---------------- orchestration ----------------

extern "C" void kernel_launch(void* const* d_in, const int* in_sizes, int n_in,
                              void* d_out, int out_size, void* d_ws, size_t ws_size,
                              hipStream_t stream) {
    const int N = N_NODES, E = N_EDGES;

    const float* x  = (const float*)d_in[0];
    const int*   ei = (const int*)d_in[1];
    const float* W1 = (const float*)d_in[2];
    const float* b1 = (const float*)d_in[3];
    const float* Wc = (const float*)d_in[4];
    const float* bc = (const float*)d_in[5];
    const float* W2 = (const float*)d_in[6];
    const float* b2 = (const float*)d_in[7];
    float* out = (float*)d_out;

    char* ws = (char*)d_ws;
    size_t off = 0;
    auto alloc = [&](size_t bytes) -> void* {
        void* p = ws + off;
        off += (bytes + 255) & ~(size_t)255;
        return p;
    };
    int*    deg       = (int*)alloc((size_t)N * 4);
    int*    cursor    = (int*)alloc((size_t)N * 4);
    int*    row_start = (int*)alloc((size_t)(N + 1) * 4);
    int*    partial   = (int*)alloc(256 * 4);
    float*  dinv      = (float*)alloc((size_t)N_PAD * 4);
    int*    csr_src   = (int*)alloc((size_t)CSR_CAP * 4);
    bf16_t* h         = (bf16_t*)alloc((size_t)N_PAD * D_HID * 2);
    bf16_t* hw        = (bf16_t*)alloc((size_t)(N_PAD + 1) * D_HID * 2);  // +1: ZROW
    bf16_t* xb        = (bf16_t*)alloc((size_t)N_PAD * D_IN * 2);
    bf16_t* W1t       = (bf16_t*)alloc((size_t)D_HID * D_IN * 2);
    bf16_t* Wct       = (bf16_t*)alloc((size_t)N_LAYERS * D_HID * D_HID * 2);
    bf16_t* W2t       = (bf16_t*)alloc((size_t)D_OUT * D_HID * 2);

    // init (zero deg/cursor, dummy csr fill, zero hw[ZROW], zero dinv pad)
    init_misc<<<(CSR_CAP + 255) / 256, 256, 0, stream>>>(deg, cursor, csr_src, dinv, hw);

    // conversions
    {
        int n = N * D_IN;
        f32_to_bf16<<<(n / 4 + 255) / 256, 256, 0, stream>>>(x, xb, n);
        transpose_all<<<dim3(16, 16, 6), dim3(32, 8), 0, stream>>>(W1, Wc, W2, W1t, Wct, W2t);
    }

    // padded CSR build
    count_deg<<<(E + 255) / 256, 256, 0, stream>>>(ei + E, deg, E);
    const int nch = (N + 1023) / 1024;
    scan_reduce<<<nch, 256, 0, stream>>>(deg, partial, N);
    scan_partials<<<1, 64, 0, stream>>>(partial, nch, row_start, N);
    scan_chunks<<<nch, 1024, 0, stream>>>(deg, partial, row_start, dinv, N);
    fill_csr<<<(E + 255) / 256, 256, 0, stream>>>(ei, E, row_start, cursor, csr_src);

    const dim3 blk(256);
    const int mg = N_PAD / 128;  // 391

    // dnn1: h = relu(x @ W1 + b1)
    gemm_tile<false, true><<<dim3(D_HID / 128, mg), blk, 0, stream>>>(
        xb, W1t, b1, nullptr, h, N_PAD, D_HID, D_IN);

    // GCN layers: hw = dinv .* (h @ Wc[i]); h = dinv .* (hw[self] + gather-sum) + bc[i]
    for (int i = 0; i < N_LAYERS; i++) {
        gemm_tile<false, false><<<dim3(D_HID / 128, mg), blk, 0, stream>>>(
            h, Wct + (size_t)i * D_HID * D_HID, nullptr, dinv, hw, N_PAD, D_HID, D_HID);
        aggregate<<<(N + 3) / 4, 256, 0, stream>>>(hw, dinv, row_start, csr_src,
                                                   bc + (size_t)i * D_HID, h, N);
    }

    // dnn2: out = h @ W2 + b2 (fp32 out)
    gemm_tile<true, false><<<dim3(D_OUT / 128, mg), blk, 0, stream>>>(
        h, W2t, b2, nullptr, out, N, D_OUT, D_HID);
}